// Round 2
// baseline (196.442 us; speedup 1.0000x reference)
//
#include <hip/hip_runtime.h>

// p/v trajectory double-scan, K = 2^23 fp32 3-vectors.
// v_i = v0 + Cc*S_i + (i+1)*g ; p_i = p0 + DT*(i+1)*v0 + DT*Cc*T_i - 0.5*DT*Cc*S_i + 0.5*DT*gz*(i+1)^2 (z)
// y_0 = f[0], y_k = f[k-1] (k>=1); S = incl prefix(y), T = incl prefix(S).
// 3 kernels: k_agg (aligned per-block aggregates), k_pre (fp64 cross-block exclusive prefixes, 1 block),
//            k_scan (stage->rake->wave scan->fused epilogue).

namespace {
constexpr int  KE    = 8388608;               // 2^23
constexpr int  CHUNK = 2048;                  // elements per block
constexpr int  NB    = KE / CHUNK;            // 4096
constexpr int  BLOCK = 256;
constexpr int  R     = CHUNK / BLOCK;         // 8
constexpr int  PLANE = CHUNK + CHUNK / R + 1; // 2305, phys(j)=j+(j>>3) conflict-free raking
constexpr float DTc = 0.01f;
constexpr float Cc  = 0.01f / 1.5f;           // DT/M
constexpr float GZ  = -0.01f * 9.81f;         // DT * (-G)
}

// ---------- Kernel A: aligned f-block aggregates A=sum f, Bw=sum r*f, E=last elem ----------
__global__ __launch_bounds__(BLOCK) void k_agg(const float* __restrict__ f,
                                               float* __restrict__ W) {
  const int b = blockIdx.x, t = threadIdx.x;
  const int lane = t & 63, wid = t >> 6;
  const float4* src = (const float4*)(f + (size_t)3 * CHUNK * b);
  float A[3] = {0.f, 0.f, 0.f}, Bw[3] = {0.f, 0.f, 0.f};
#pragma unroll
  for (int it = 0; it < 2; ++it) {
    int q3 = it * BLOCK + t;                  // triple index 0..511, elems 4q3..4q3+3
    float4 d0 = src[3 * q3], d1 = src[3 * q3 + 1], d2 = src[3 * q3 + 2];
    float j0 = (float)(4 * q3), j1 = j0 + 1.f, j2 = j0 + 2.f, j3 = j0 + 3.f;
    A[0] += d0.x; Bw[0] += j0 * d0.x;  A[1] += d0.y; Bw[1] += j0 * d0.y;  A[2] += d0.z; Bw[2] += j0 * d0.z;
    A[0] += d0.w; Bw[0] += j1 * d0.w;  A[1] += d1.x; Bw[1] += j1 * d1.x;  A[2] += d1.y; Bw[2] += j1 * d1.y;
    A[0] += d1.z; Bw[0] += j2 * d1.z;  A[1] += d1.w; Bw[1] += j2 * d1.w;  A[2] += d2.x; Bw[2] += j2 * d2.x;
    A[0] += d2.y; Bw[0] += j3 * d2.y;  A[1] += d2.z; Bw[1] += j3 * d2.z;  A[2] += d2.w; Bw[2] += j3 * d2.w;
    if (q3 == 2 * BLOCK - 1) {                // last element of block -> E
      W[(6 + 0) * NB + b] = d2.y; W[(6 + 1) * NB + b] = d2.z; W[(6 + 2) * NB + b] = d2.w;
    }
  }
#pragma unroll
  for (int d = 32; d >= 1; d >>= 1) {
#pragma unroll
    for (int q = 0; q < 3; ++q) {
      A[q] += __shfl_down(A[q], d);
      Bw[q] += __shfl_down(Bw[q], d);
    }
  }
  __shared__ float wag[4][6];
  if (lane == 0) {
#pragma unroll
    for (int q = 0; q < 3; ++q) { wag[wid][q] = A[q]; wag[wid][3 + q] = Bw[q]; }
  }
  __syncthreads();
  if (t == 0) {
#pragma unroll
    for (int q = 0; q < 3; ++q) {
      W[q * NB + b]       = wag[0][q] + wag[1][q] + wag[2][q] + wag[3][q];
      W[(3 + q) * NB + b] = wag[0][3 + q] + wag[1][3 + q] + wag[2][3 + q] + wag[3][3 + q];
    }
  }
}

// ---------- Kernel B: exclusive cross-block prefixes (Sg,Tg) in fp64, one wave ----------
// Sg_b = f0 + sum_{c<b} A_c - E_{b-1}  (b>=1; 0 for b=0)
// Tg_b = n*f0 + (n-1)*sum A - CHUNK*sum(c*A_c) - sum Bw,  n = b*CHUNK
__global__ __launch_bounds__(64) void k_pre(const float* __restrict__ W,
                                            const float* __restrict__ f,
                                            float* __restrict__ W2) {
  const int lane = threadIdx.x;               // 64 lanes, 64 blocks each
  const int c0 = lane * (NB / 64);
  double la[3] = {0, 0, 0}, lwa[3] = {0, 0, 0}, lb[3] = {0, 0, 0};
  for (int k = 0; k < NB / 64; ++k) {
    int c = c0 + k;
#pragma unroll
    for (int q = 0; q < 3; ++q) {
      double a = (double)W[q * NB + c];
      la[q] += a; lwa[q] += (double)c * a; lb[q] += (double)W[(3 + q) * NB + c];
    }
  }
  // inclusive KS scan (plain add) over 64 lanes, then exclusive shift
#pragma unroll
  for (int d = 1; d < 64; d <<= 1) {
    double pa[3], pw[3], pb[3];
#pragma unroll
    for (int q = 0; q < 3; ++q) { pa[q] = __shfl_up(la[q], d); pw[q] = __shfl_up(lwa[q], d); pb[q] = __shfl_up(lb[q], d); }
    if (lane >= d) {
#pragma unroll
      for (int q = 0; q < 3; ++q) { la[q] += pa[q]; lwa[q] += pw[q]; lb[q] += pb[q]; }
    }
  }
  double ra[3], rwa[3], rb[3];
#pragma unroll
  for (int q = 0; q < 3; ++q) { ra[q] = __shfl_up(la[q], 1); rwa[q] = __shfl_up(lwa[q], 1); rb[q] = __shfl_up(lb[q], 1); }
  if (lane == 0) {
#pragma unroll
    for (int q = 0; q < 3; ++q) { ra[q] = 0.0; rwa[q] = 0.0; rb[q] = 0.0; }
  }
  double f0[3] = {(double)f[0], (double)f[1], (double)f[2]};
  for (int k = 0; k < NB / 64; ++k) {
    int b = c0 + k;
    double n = (double)b * CHUNK;
#pragma unroll
    for (int q = 0; q < 3; ++q) {
      double Sg = (b == 0) ? 0.0 : (f0[q] + ra[q] - (double)W[(6 + q) * NB + (b - 1)]);
      double Tg = n * f0[q] + (n - 1.0) * ra[q] - (double)CHUNK * rwa[q] - rb[q];
      W2[6 * b + q]     = (float)Sg;
      W2[6 * b + 3 + q] = (float)Tg;
      double a = (double)W[q * NB + b];
      ra[q] += a; rwa[q] += (double)b * a; rb[q] += (double)W[(3 + q) * NB + b];
    }
  }
}

// ---------- Kernel C: per-block scan + fused epilogue ----------
__global__ __launch_bounds__(BLOCK, 4) void k_scan(const float* __restrict__ f,
                                                   const float* __restrict__ W2,
                                                   const float* __restrict__ p0v,
                                                   const float* __restrict__ v0v,
                                                   float* __restrict__ out) {
  const int b = blockIdx.x, t = threadIdx.x;
  const int lane = t & 63, wid = t >> 6;
  const long start = (long)b * CHUNK;

  __shared__ float sm[3 * PLANE];
  __shared__ float wag[4][6];

  float Sg[3], Tg[3];
#pragma unroll
  for (int q = 0; q < 3; ++q) { Sg[q] = W2[6 * b + q]; Tg[q] = W2[6 * b + 3 + q]; }

  // stage y into padded LDS planes (float4 loads, de-interleave)
  {
    const float4* src = (const float4*)(f + 3 * start);
#pragma unroll
    for (int it = 0; it < (3 * CHUNK / 4) / BLOCK; ++it) {  // 6
      int q4 = it * BLOCK + t;
      float4 d = src[q4];
      int s0 = 4 * q4;
      float vals[4] = {d.x, d.y, d.z, d.w};
#pragma unroll
      for (int r = 0; r < 4; ++r) {
        int s = s0 + r;
        int j = s / 3 + 1;          // f[start + s/3] supplies y_{s/3+1}
        int c = s - (j - 1) * 3;
        if (j < CHUNK) sm[c * PLANE + j + (j >> 3)] = vals[r];
      }
    }
    if (t == 0) {                   // y_0 = f[max(start-1,0)]
      long m = start - 1; if (m < 0) m = 0;
#pragma unroll
      for (int q = 0; q < 3; ++q) sm[q * PLANE + 0] = f[3 * m + q];
    }
  }
  __syncthreads();

  // per-thread (Sum, Ttot) rake over 8 contiguous padded floats (base 9t)
  float tS[3] = {0, 0, 0}, tT[3] = {0, 0, 0};
#pragma unroll
  for (int e = 0; e < R; ++e) {
    float wt = (float)(R - e);
#pragma unroll
    for (int q = 0; q < 3; ++q) {
      float v = sm[q * PLANE + 9 * t + e];
      tS[q] += v; tT[q] += wt * v;
    }
  }
  // Kogge-Stone over 64 lanes; updating lane's segment length is exactly R*d
#pragma unroll
  for (int d = 1; d < 64; d <<= 1) {
    float pS[3], pT[3];
#pragma unroll
    for (int q = 0; q < 3; ++q) { pS[q] = __shfl_up(tS[q], d); pT[q] = __shfl_up(tT[q], d); }
    if (lane >= d) {
      const float Ld = (float)(R * d);
#pragma unroll
      for (int q = 0; q < 3; ++q) { tT[q] = pT[q] + Ld * pS[q] + tT[q]; tS[q] += pS[q]; }
    }
  }
  // lane-exclusive within wave
  float eS[3], eT[3];
#pragma unroll
  for (int q = 0; q < 3; ++q) { eS[q] = __shfl_up(tS[q], 1); eT[q] = __shfl_up(tT[q], 1); }
  if (lane == 0) {
#pragma unroll
    for (int q = 0; q < 3; ++q) { eS[q] = 0.f; eT[q] = 0.f; }
  }
  if (lane == 63) {
#pragma unroll
    for (int q = 0; q < 3; ++q) { wag[wid][q] = tS[q]; wag[wid][3 + q] = tT[q]; }
  }
  __syncthreads();
  float oS[3] = {0, 0, 0}, oT[3] = {0, 0, 0};
  for (int w = 0; w < wid; ++w) {
#pragma unroll
    for (int q = 0; q < 3; ++q) oT[q] = oT[q] + 512.0f * oS[q] + wag[w][3 + q];
#pragma unroll
    for (int q = 0; q < 3; ++q) oS[q] = oS[q] + wag[w][q];
  }
  // absolute thread-exclusive (S1,T1)
  float S1[3], T1[3];
  const float Lex = (float)(R * lane);
#pragma unroll
  for (int q = 0; q < 3; ++q) {
    float Sb = oS[q] + eS[q];
    float Tb = oT[q] + Lex * oS[q] + eT[q];
    S1[q] = Sg[q] + Sb;
    T1[q] = Tg[q] + (float)(R * t) * Sg[q] + Tb;
  }

  // serial per-element scan + fused epilogue; emit float4s per 4-element group
  const float p0x = p0v[0], p0y = p0v[1], p0z = p0v[2];
  const float v0x = v0v[0], v0y = v0v[1], v0z = v0v[2];
  const float a1 = DTc * Cc, a2 = 0.5f * DTc * Cc, c3 = 0.5f * DTc * GZ;
  const int j0 = t * R;
  float sr[3] = {0, 0, 0}, tr[3] = {0, 0, 0};
  float4* pw = (float4*)(out + 3 * (start + j0));
  float4* vw = (float4*)(out + (size_t)3 * KE + 3 * (start + j0));
#pragma unroll
  for (int g = 0; g < 2; ++g) {
    float pe[12], ve[12];
#pragma unroll
    for (int e4 = 0; e4 < 4; ++e4) {
      int e = 4 * g + e4;
      float n1 = (float)(int)(start + j0 + e + 1);   // < 2^24, exact
      float S_[3], T_[3];
#pragma unroll
      for (int q = 0; q < 3; ++q) {
        float v = sm[q * PLANE + 9 * t + e];
        sr[q] += v; tr[q] += sr[q];
        S_[q] = S1[q] + sr[q];
        T_[q] = T1[q] + (float)(e + 1) * S1[q] + tr[q];
      }
      ve[3 * e4 + 0] = v0x + Cc * S_[0];
      ve[3 * e4 + 1] = v0y + Cc * S_[1];
      ve[3 * e4 + 2] = v0z + Cc * S_[2] + GZ * n1;
      pe[3 * e4 + 0] = p0x + DTc * n1 * v0x + a1 * T_[0] - a2 * S_[0];
      pe[3 * e4 + 1] = p0y + DTc * n1 * v0y + a1 * T_[1] - a2 * S_[1];
      pe[3 * e4 + 2] = p0z + DTc * n1 * v0z + a1 * T_[2] - a2 * S_[2] + c3 * n1 * n1;
    }
    pw[3 * g + 0] = make_float4(pe[0], pe[1], pe[2],  pe[3]);
    pw[3 * g + 1] = make_float4(pe[4], pe[5], pe[6],  pe[7]);
    pw[3 * g + 2] = make_float4(pe[8], pe[9], pe[10], pe[11]);
    vw[3 * g + 0] = make_float4(ve[0], ve[1], ve[2],  ve[3]);
    vw[3 * g + 1] = make_float4(ve[4], ve[5], ve[6],  ve[7]);
    vw[3 * g + 2] = make_float4(ve[8], ve[9], ve[10], ve[11]);
  }
}

extern "C" void kernel_launch(void* const* d_in, const int* in_sizes, int n_in,
                              void* d_out, int out_size, void* d_ws, size_t ws_size,
                              hipStream_t stream) {
  const float* f  = (const float*)d_in[0];
  const float* p0 = (const float*)d_in[1];
  const float* v0 = (const float*)d_in[2];
  float* out = (float*)d_out;
  float* W   = (float*)d_ws;            // 9*NB floats: A[3][NB], Bw[3][NB], E[3][NB]
  float* W2  = W + 9 * NB;              // 6*NB floats: per-block (Sg[3], Tg[3])
  k_agg <<<NB, BLOCK, 0, stream>>>(f, W);
  k_pre <<<1, 64, 0, stream>>>(W, f, W2);
  k_scan<<<NB, BLOCK, 0, stream>>>(f, W2, p0, v0, out);
}